// Round 1
// baseline (196.060 us; speedup 1.0000x reference)
//
#include <hip/hip_runtime.h>
#include <math.h>

#define NN 50000
#define DEG 32
#define FDIM 128
#define NCLS 16
#define LN_EPS 1e-5f
#define CLAMP_MIN 1e-5f

// ---------------- Kernel 1: per-node argmax of logits ----------------
__global__ __launch_bounds__(256) void k_pred(const float* __restrict__ logits,
                                              int* __restrict__ pred, int n) {
    int i = blockIdx.x * 256 + threadIdx.x;
    if (i >= n) return;
    const float4* lp = (const float4*)(logits + (long)i * NCLS);
    float best = -INFINITY;
    int bi = 0;
#pragma unroll
    for (int q = 0; q < 4; ++q) {
        float4 v = lp[q];
        float vv[4] = {v.x, v.y, v.z, v.w};
#pragma unroll
        for (int r = 0; r < 4; ++r) {
            // strict > keeps FIRST max index (matches jnp.argmax)
            if (vv[r] > best) { best = vv[r]; bi = q * 4 + r; }
        }
    }
    pred[i] = bi;
}

// ---------------- Kernel 2: f1/f2 + per-block partial sums ----------------
__global__ __launch_bounds__(256) void k_feats(const int* __restrict__ nbr,
                                               const int* __restrict__ pred,
                                               float* __restrict__ f1,
                                               float* __restrict__ f2,
                                               float* __restrict__ partials,
                                               int n) {
    int i = blockIdx.x * 256 + threadIdx.x;
    float v1 = 0.f, v2 = 0.f;
    if (i < n) {
        // histogram of 32 neighbor preds packed 8 bits/class into two u64s
        unsigned long long lo = 0ull, hi = 0ull;
        const int4* np = (const int4*)(nbr + (long)i * DEG);
#pragma unroll
        for (int q = 0; q < 8; ++q) {
            int4 k4 = np[q];
            int ks[4] = {k4.x, k4.y, k4.z, k4.w};
#pragma unroll
            for (int r = 0; r < 4; ++r) {
                int p = pred[ks[r]];
                unsigned long long inc = 1ull << ((p & 7) * 8);
                if (p < 8) lo += inc; else hi += inc;
            }
        }
        int cp = pred[i];
        unsigned long long src = (cp < 8) ? lo : hi;
        v1 = (float)((src >> ((cp & 7) * 8)) & 0xffull);  // f1 = hist[center_pred]
        float ent = 0.f;
#pragma unroll
        for (int c = 0; c < NCLS; ++c) {
            unsigned long long s = (c < 8) ? lo : hi;
            float cnt = (float)((s >> ((c & 7) * 8)) & 0xffull);
            float x = fmaxf(cnt, CLAMP_MIN);  // zeros clip to 1e-5, contribute too
            ent -= x * logf(x);
        }
        v2 = ent;
        f1[i] = v1;
        f2[i] = v2;
    }
    // block-reduce {sum f1, sum f1^2, sum f2, sum f2^2}
    float s0 = v1, s1 = v1 * v1, s2 = v2, s3 = v2 * v2;
#pragma unroll
    for (int off = 32; off > 0; off >>= 1) {  // wave = 64 lanes
        s0 += __shfl_down(s0, off);
        s1 += __shfl_down(s1, off);
        s2 += __shfl_down(s2, off);
        s3 += __shfl_down(s3, off);
    }
    __shared__ float red[4][4];
    int wid = threadIdx.x >> 6;
    if ((threadIdx.x & 63) == 0) {
        red[wid][0] = s0; red[wid][1] = s1; red[wid][2] = s2; red[wid][3] = s3;
    }
    __syncthreads();
    if (threadIdx.x == 0) {
        float t0 = 0.f, t1 = 0.f, t2 = 0.f, t3 = 0.f;
#pragma unroll
        for (int w = 0; w < 4; ++w) {
            t0 += red[w][0]; t1 += red[w][1]; t2 += red[w][2]; t3 += red[w][3];
        }
        float* pp = partials + (long)blockIdx.x * 4;
        pp[0] = t0; pp[1] = t1; pp[2] = t2; pp[3] = t3;
    }
}

// ---------------- Kernel 3: finalize LayerNorm params (1 block) ----------------
__global__ __launch_bounds__(256) void k_params(const float* __restrict__ partials,
                                                int nb, float* __restrict__ params) {
    double s0 = 0, s1 = 0, s2 = 0, s3 = 0;
    for (int b = threadIdx.x; b < nb; b += 256) {
        const float* pp = partials + (long)b * 4;
        s0 += (double)pp[0]; s1 += (double)pp[1];
        s2 += (double)pp[2]; s3 += (double)pp[3];
    }
#pragma unroll
    for (int off = 32; off > 0; off >>= 1) {
        s0 += __shfl_down(s0, off);
        s1 += __shfl_down(s1, off);
        s2 += __shfl_down(s2, off);
        s3 += __shfl_down(s3, off);
    }
    __shared__ double red[4][4];
    int wid = threadIdx.x >> 6;
    if ((threadIdx.x & 63) == 0) {
        red[wid][0] = s0; red[wid][1] = s1; red[wid][2] = s2; red[wid][3] = s3;
    }
    __syncthreads();
    if (threadIdx.x == 0) {
        double t0 = 0, t1 = 0, t2 = 0, t3 = 0;
        for (int w = 0; w < 4; ++w) {
            t0 += red[w][0]; t1 += red[w][1]; t2 += red[w][2]; t3 += red[w][3];
        }
        double inv_n = 1.0 / (double)NN;
        double m1 = t0 * inv_n;
        double var1 = t1 * inv_n - m1 * m1;  // biased var, matches jnp.var
        double m2 = t2 * inv_n;
        double var2 = t3 * inv_n - m2 * m2;
        params[0] = (float)m1;
        params[1] = (float)(1.0 / sqrt(var1 + (double)LN_EPS));
        params[2] = (float)m2;
        params[3] = (float)(1.0 / sqrt(var2 + (double)LN_EPS));
    }
}

// ---------------- Kernel 4: z/gate + neighbor-feature aggregation ----------------
// 32 lanes per node: lane = one float4 column of F=128; neighbor index
// broadcast via __shfl(width=32) so each gather reads one contiguous 512B row.
__global__ __launch_bounds__(256) void k_agg(const float* __restrict__ h,
                                             const int* __restrict__ nbr,
                                             const float* __restrict__ old_z,
                                             const float* __restrict__ tau1,
                                             const float* __restrict__ tau2,
                                             const float* __restrict__ f1,
                                             const float* __restrict__ f2,
                                             const float* __restrict__ params,
                                             float* __restrict__ out_h,
                                             float* __restrict__ out_z, int n) {
    int t = blockIdx.x * 256 + threadIdx.x;
    int node = t >> 5;
    int lane = threadIdx.x & 31;
    if (node >= n) return;
    int k = nbr[(long)node * DEG + lane];  // one neighbor index per lane
    float4 acc = make_float4(0.f, 0.f, 0.f, 0.f);
#pragma unroll
    for (int j = 0; j < DEG; ++j) {
        int kj = __shfl(k, j, 32);
        float4 v = ((const float4*)(h + (long)kj * FDIM))[lane];
        acc.x += v.x; acc.y += v.y; acc.z += v.z; acc.w += v.w;
    }
    // gate (all 32 lanes compute the same cheap scalar path; loads broadcast)
    float m1 = params[0], i1 = params[1], m2 = params[2], i2 = params[3];
    float a = (f1[node] - m1) * i1 - tau1[0];
    float b = (f2[node] - m2) * i2 - tau2[0];
    // sigmoid(-a)*sigmoid(-b) = 1 / ((1+e^a)(1+e^b))
    float z = 1.f / ((1.f + expf(a)) * (1.f + expf(b)));
    float gate = fminf(old_z[node], z);
    float4 hv = ((const float4*)(h + (long)node * FDIM))[lane];
    float4 o;
    o.x = hv.x + gate * fmaxf(acc.x, 0.f);
    o.y = hv.y + gate * fmaxf(acc.y, 0.f);
    o.z = hv.z + gate * fmaxf(acc.z, 0.f);
    o.w = hv.w + gate * fmaxf(acc.w, 0.f);
    ((float4*)(out_h + (long)node * FDIM))[lane] = o;
    if (lane == 0) out_z[node] = z;
}

extern "C" void kernel_launch(void* const* d_in, const int* in_sizes, int n_in,
                              void* d_out, int out_size, void* d_ws, size_t ws_size,
                              hipStream_t stream) {
    const float* h      = (const float*)d_in[0];
    const float* logits = (const float*)d_in[1];
    const float* old_z  = (const float*)d_in[2];
    const float* tau1   = (const float*)d_in[3];
    const float* tau2   = (const float*)d_in[4];
    const int*   nbr    = (const int*)d_in[5];

    // workspace layout (~614 KB total)
    char* ws = (char*)d_ws;
    float* params   = (float*)ws;                     // 4 floats
    float* partials = (float*)(ws + 64);              // NB*4 floats (<3.2 KB)
    int*   pred     = (int*)(ws + 4096);              // NN ints   (200 KB)
    float* f1       = (float*)(ws + 4096 + 204800);   // NN floats (200 KB)
    float* f2       = (float*)(ws + 4096 + 409600);   // NN floats (200 KB)

    float* out_h = (float*)d_out;
    float* out_z = out_h + (long)NN * FDIM;

    int NB = (NN + 255) / 256;  // 196
    k_pred  <<<NB, 256, 0, stream>>>(logits, pred, NN);
    k_feats <<<NB, 256, 0, stream>>>(nbr, pred, f1, f2, partials, NN);
    k_params<<<1, 256, 0, stream>>>(partials, NB, params);
    k_agg   <<<(NN * DEG + 255) / 256, 256, 0, stream>>>(h, nbr, old_z, tau1, tau2,
                                                         f1, f2, params, out_h, out_z, NN);
}

// Round 2
// 151.576 us; speedup vs baseline: 1.2935x; 1.2935x over previous
//
#include <hip/hip_runtime.h>
#include <math.h>

#define NN 50000
#define DEG 32
#define FDIM 128
#define NCLS 16
#define LN_EPS 1e-5f
#define CLAMP_MIN 1e-5f

// ---------------- Kernel 1: per-node argmax of logits ----------------
__global__ __launch_bounds__(256) void k_pred(const float* __restrict__ logits,
                                              int* __restrict__ pred, int n) {
    int i = blockIdx.x * 256 + threadIdx.x;
    if (i >= n) return;
    const float4* lp = (const float4*)(logits + (long)i * NCLS);
    float best = -INFINITY;
    int bi = 0;
#pragma unroll
    for (int q = 0; q < 4; ++q) {
        float4 v = lp[q];
        float vv[4] = {v.x, v.y, v.z, v.w};
#pragma unroll
        for (int r = 0; r < 4; ++r) {
            // strict > keeps FIRST max index (matches jnp.argmax)
            if (vv[r] > best) { best = vv[r]; bi = q * 4 + r; }
        }
    }
    pred[i] = bi;
}

// ---------------- Kernel 1b: h (fp32) -> bf16 copy, RNE, pair-packed ----------------
__device__ inline unsigned bf_rne(float x) {
    unsigned u = __float_as_uint(x);
    u += 0x7fffu + ((u >> 16) & 1u);  // round-to-nearest-even
    return u >> 16;
}
// pack feature pair (e0,e1) -> (rne(e0) | rne(e1)<<16)
__global__ __launch_bounds__(256) void k_conv(const float* __restrict__ h,
                                              unsigned* __restrict__ hb_u32,
                                              int ngroups /* = NN*FDIM/8 */) {
    int stride = gridDim.x * 256;
    for (int g = blockIdx.x * 256 + threadIdx.x; g < ngroups; g += stride) {
        const float4* src = (const float4*)(h + (long)g * 8);
        float4 a = src[0], b = src[1];
        uint4 o;
        o.x = bf_rne(a.x) | (bf_rne(a.y) << 16);
        o.y = bf_rne(a.z) | (bf_rne(a.w) << 16);
        o.z = bf_rne(b.x) | (bf_rne(b.y) << 16);
        o.w = bf_rne(b.z) | (bf_rne(b.w) << 16);
        ((uint4*)hb_u32)[g] = o;
    }
}

// ---------------- Kernel 2: f1/f2 + per-block partial sums ----------------
__global__ __launch_bounds__(256) void k_feats(const int* __restrict__ nbr,
                                               const int* __restrict__ pred,
                                               float* __restrict__ f1,
                                               float* __restrict__ f2,
                                               float* __restrict__ partials,
                                               int n) {
    int i = blockIdx.x * 256 + threadIdx.x;
    float v1 = 0.f, v2 = 0.f;
    if (i < n) {
        // histogram of 32 neighbor preds packed 8 bits/class into two u64s
        unsigned long long lo = 0ull, hi = 0ull;
        const int4* np = (const int4*)(nbr + (long)i * DEG);
#pragma unroll
        for (int q = 0; q < 8; ++q) {
            int4 k4 = np[q];
            int ks[4] = {k4.x, k4.y, k4.z, k4.w};
#pragma unroll
            for (int r = 0; r < 4; ++r) {
                int p = pred[ks[r]];
                unsigned long long inc = 1ull << ((p & 7) * 8);
                if (p < 8) lo += inc; else hi += inc;
            }
        }
        int cp = pred[i];
        unsigned long long src = (cp < 8) ? lo : hi;
        v1 = (float)((src >> ((cp & 7) * 8)) & 0xffull);  // f1 = hist[center_pred]
        float ent = 0.f;
#pragma unroll
        for (int c = 0; c < NCLS; ++c) {
            unsigned long long s = (c < 8) ? lo : hi;
            float cnt = (float)((s >> ((c & 7) * 8)) & 0xffull);
            float x = fmaxf(cnt, CLAMP_MIN);  // zeros clip to 1e-5, contribute too
            ent -= x * logf(x);
        }
        v2 = ent;
        f1[i] = v1;
        f2[i] = v2;
    }
    // block-reduce {sum f1, sum f1^2, sum f2, sum f2^2}
    float s0 = v1, s1 = v1 * v1, s2 = v2, s3 = v2 * v2;
#pragma unroll
    for (int off = 32; off > 0; off >>= 1) {  // wave = 64 lanes
        s0 += __shfl_down(s0, off);
        s1 += __shfl_down(s1, off);
        s2 += __shfl_down(s2, off);
        s3 += __shfl_down(s3, off);
    }
    __shared__ float red[4][4];
    int wid = threadIdx.x >> 6;
    if ((threadIdx.x & 63) == 0) {
        red[wid][0] = s0; red[wid][1] = s1; red[wid][2] = s2; red[wid][3] = s3;
    }
    __syncthreads();
    if (threadIdx.x == 0) {
        float t0 = 0.f, t1 = 0.f, t2 = 0.f, t3 = 0.f;
#pragma unroll
        for (int w = 0; w < 4; ++w) {
            t0 += red[w][0]; t1 += red[w][1]; t2 += red[w][2]; t3 += red[w][3];
        }
        float* pp = partials + (long)blockIdx.x * 4;
        pp[0] = t0; pp[1] = t1; pp[2] = t2; pp[3] = t3;
    }
}

// ---------------- Kernel 3: finalize LayerNorm params (1 block) ----------------
__global__ __launch_bounds__(256) void k_params(const float* __restrict__ partials,
                                                int nb, float* __restrict__ params) {
    double s0 = 0, s1 = 0, s2 = 0, s3 = 0;
    for (int b = threadIdx.x; b < nb; b += 256) {
        const float* pp = partials + (long)b * 4;
        s0 += (double)pp[0]; s1 += (double)pp[1];
        s2 += (double)pp[2]; s3 += (double)pp[3];
    }
#pragma unroll
    for (int off = 32; off > 0; off >>= 1) {
        s0 += __shfl_down(s0, off);
        s1 += __shfl_down(s1, off);
        s2 += __shfl_down(s2, off);
        s3 += __shfl_down(s3, off);
    }
    __shared__ double red[4][4];
    int wid = threadIdx.x >> 6;
    if ((threadIdx.x & 63) == 0) {
        red[wid][0] = s0; red[wid][1] = s1; red[wid][2] = s2; red[wid][3] = s3;
    }
    __syncthreads();
    if (threadIdx.x == 0) {
        double t0 = 0, t1 = 0, t2 = 0, t3 = 0;
        for (int w = 0; w < 4; ++w) {
            t0 += red[w][0]; t1 += red[w][1]; t2 += red[w][2]; t3 += red[w][3];
        }
        double inv_n = 1.0 / (double)NN;
        double m1 = t0 * inv_n;
        double var1 = t1 * inv_n - m1 * m1;  // biased var, matches jnp.var
        double m2 = t2 * inv_n;
        double var2 = t3 * inv_n - m2 * m2;
        params[0] = (float)m1;
        params[1] = (float)(1.0 / sqrt(var1 + (double)LN_EPS));
        params[2] = (float)m2;
        params[3] = (float)(1.0 / sqrt(var2 + (double)LN_EPS));
    }
}

// ---------------- gate helper (shared by both agg variants) ----------------
__device__ inline float gate_z(const float* __restrict__ params,
                               const float* __restrict__ tau1,
                               const float* __restrict__ tau2,
                               float vf1, float vf2) {
    float a = (vf1 - params[0]) * params[1] - tau1[0];
    float b = (vf2 - params[2]) * params[3] - tau2[0];
    // sigmoid(-a)*sigmoid(-b) = 1 / ((1+e^a)(1+e^b))
    return 1.f / ((1.f + expf(a)) * (1.f + expf(b)));
}

// ---------------- Kernel 4 (bf16 gather): z/gate + neighbor aggregation ----------------
// 32 lanes per node; lane = one 4-feature column (uint2 = 4 bf16, 8B/lane ->
// one fully-contiguous 256B row per gather instruction, index via __shfl).
__global__ __launch_bounds__(256) void k_agg_bf(const float* __restrict__ h,
                                                const unsigned* __restrict__ hb,
                                                const int* __restrict__ nbr,
                                                const float* __restrict__ old_z,
                                                const float* __restrict__ tau1,
                                                const float* __restrict__ tau2,
                                                const float* __restrict__ f1,
                                                const float* __restrict__ f2,
                                                const float* __restrict__ params,
                                                float* __restrict__ out_h,
                                                float* __restrict__ out_z, int n) {
    int t = blockIdx.x * 256 + threadIdx.x;
    int node = t >> 5;
    int lane = threadIdx.x & 31;
    if (node >= n) return;
    int k = nbr[(long)node * DEG + lane];  // one neighbor index per lane
    float4 acc = make_float4(0.f, 0.f, 0.f, 0.f);
#pragma unroll
    for (int j = 0; j < DEG; ++j) {
        int kj = __shfl(k, j, 32);
        uint2 v = ((const uint2*)(hb + (long)kj * (FDIM / 2)))[lane];
        acc.x += __uint_as_float(v.x << 16);
        acc.y += __uint_as_float(v.x & 0xffff0000u);
        acc.z += __uint_as_float(v.y << 16);
        acc.w += __uint_as_float(v.y & 0xffff0000u);
    }
    float z = gate_z(params, tau1, tau2, f1[node], f2[node]);
    float gate = fminf(old_z[node], z);
    float4 hv = ((const float4*)(h + (long)node * FDIM))[lane];
    float4 o;
    o.x = hv.x + gate * fmaxf(acc.x, 0.f);
    o.y = hv.y + gate * fmaxf(acc.y, 0.f);
    o.z = hv.z + gate * fmaxf(acc.z, 0.f);
    o.w = hv.w + gate * fmaxf(acc.w, 0.f);
    ((float4*)(out_h + (long)node * FDIM))[lane] = o;
    if (lane == 0) out_z[node] = z;
}

// ---------------- Kernel 4 fallback (fp32 gather), used if ws too small ----------------
__global__ __launch_bounds__(256) void k_agg(const float* __restrict__ h,
                                             const int* __restrict__ nbr,
                                             const float* __restrict__ old_z,
                                             const float* __restrict__ tau1,
                                             const float* __restrict__ tau2,
                                             const float* __restrict__ f1,
                                             const float* __restrict__ f2,
                                             const float* __restrict__ params,
                                             float* __restrict__ out_h,
                                             float* __restrict__ out_z, int n) {
    int t = blockIdx.x * 256 + threadIdx.x;
    int node = t >> 5;
    int lane = threadIdx.x & 31;
    if (node >= n) return;
    int k = nbr[(long)node * DEG + lane];
    float4 acc = make_float4(0.f, 0.f, 0.f, 0.f);
#pragma unroll
    for (int j = 0; j < DEG; ++j) {
        int kj = __shfl(k, j, 32);
        float4 v = ((const float4*)(h + (long)kj * FDIM))[lane];
        acc.x += v.x; acc.y += v.y; acc.z += v.z; acc.w += v.w;
    }
    float z = gate_z(params, tau1, tau2, f1[node], f2[node]);
    float gate = fminf(old_z[node], z);
    float4 hv = ((const float4*)(h + (long)node * FDIM))[lane];
    float4 o;
    o.x = hv.x + gate * fmaxf(acc.x, 0.f);
    o.y = hv.y + gate * fmaxf(acc.y, 0.f);
    o.z = hv.z + gate * fmaxf(acc.z, 0.f);
    o.w = hv.w + gate * fmaxf(acc.w, 0.f);
    ((float4*)(out_h + (long)node * FDIM))[lane] = o;
    if (lane == 0) out_z[node] = z;
}

extern "C" void kernel_launch(void* const* d_in, const int* in_sizes, int n_in,
                              void* d_out, int out_size, void* d_ws, size_t ws_size,
                              hipStream_t stream) {
    const float* h      = (const float*)d_in[0];
    const float* logits = (const float*)d_in[1];
    const float* old_z  = (const float*)d_in[2];
    const float* tau1   = (const float*)d_in[3];
    const float* tau2   = (const float*)d_in[4];
    const int*   nbr    = (const int*)d_in[5];

    // workspace layout
    char* ws = (char*)d_ws;
    float*    params   = (float*)ws;                    // 4 floats
    float*    partials = (float*)(ws + 64);             // NB*4 floats (<3.2 KB)
    int*      pred     = (int*)(ws + 4096);             // NN ints   (200 KB)
    float*    f1       = (float*)(ws + 4096 + 204800);  // NN floats (200 KB)
    float*    f2       = (float*)(ws + 4096 + 409600);  // NN floats (200 KB)
    unsigned* hb       = (unsigned*)(ws + 1048576);     // NN*FDIM bf16 = 12.8 MB
    size_t need = 1048576 + (size_t)NN * FDIM * 2;
    bool use_bf = (ws_size >= need);

    float* out_h = (float*)d_out;
    float* out_z = out_h + (long)NN * FDIM;

    int NB = (NN + 255) / 256;  // 196
    k_pred  <<<NB, 256, 0, stream>>>(logits, pred, NN);
    if (use_bf) {
        k_conv<<<512, 256, 0, stream>>>(h, hb, NN * FDIM / 8);
    }
    k_feats <<<NB, 256, 0, stream>>>(nbr, pred, f1, f2, partials, NN);
    k_params<<<1, 256, 0, stream>>>(partials, NB, params);
    int AB = (NN * DEG + 255) / 256;
    if (use_bf) {
        k_agg_bf<<<AB, 256, 0, stream>>>(h, hb, nbr, old_z, tau1, tau2,
                                         f1, f2, params, out_h, out_z, NN);
    } else {
        k_agg<<<AB, 256, 0, stream>>>(h, nbr, old_z, tau1, tau2,
                                      f1, f2, params, out_h, out_z, NN);
    }
}